// Round 1
// baseline (320.657 us; speedup 1.0000x reference)
//
#include <hip/hip_runtime.h>

#define DIM 768
#define NEG_SLOPE 0.2f

typedef unsigned short ushort_t;
typedef short short8 __attribute__((ext_vector_type(8)));
typedef float floatx4 __attribute__((ext_vector_type(4)));

__device__ __forceinline__ ushort_t f32_to_bf16(float f) {
  unsigned int b = __float_as_uint(f);
  b += 0x7FFFu + ((b >> 16) & 1u);   // RNE
  return (ushort_t)(b >> 16);
}

// ---------------- CSR build (by destination, self-loops appended) ----------------
__global__ void hist_kernel(const int* __restrict__ ei, int* __restrict__ deg,
                            int E, int Etot) {
  int e = blockIdx.x * 256 + threadIdx.x;
  if (e >= Etot) return;
  int d = (e < E) ? ei[E + e] : (e - E);
  atomicAdd(&deg[d], 1);
}

__global__ void scan_kernel(const int* __restrict__ deg, int* __restrict__ rowstart,
                            int* __restrict__ cursor, int n, int etot) {
  __shared__ int part[256];
  int tid = threadIdx.x;
  int chunk = (n + 255) / 256;
  int lo = tid * chunk;
  int hi = min(lo + chunk, n);
  int s = 0;
  for (int i = lo; i < hi; ++i) s += deg[i];
  part[tid] = s;
  __syncthreads();
  for (int off = 1; off < 256; off <<= 1) {
    int v = part[tid];
    int add = (tid >= off) ? part[tid - off] : 0;
    __syncthreads();
    part[tid] = v + add;
    __syncthreads();
  }
  int run = (tid == 0) ? 0 : part[tid - 1];
  for (int i = lo; i < hi; ++i) {
    rowstart[i] = run;
    cursor[i] = run;
    run += deg[i];
  }
  if (tid == 0) rowstart[n] = etot;
}

__global__ void fill_kernel(const int* __restrict__ ei, int* __restrict__ cursor,
                            int* __restrict__ col, int E, int Etot) {
  int e = blockIdx.x * 256 + threadIdx.x;
  if (e >= Etot) return;
  int s, d;
  if (e < E) { s = ei[e]; d = ei[E + e]; }
  else       { s = e - E; d = e - E; }
  int pos = atomicAdd(&cursor[d], 1);
  col[pos] = s;
}

// ---------------- fp32 -> bf16 cast ----------------
__global__ void cast_kernel(const float* __restrict__ in, ushort_t* __restrict__ out, int n) {
  int i = blockIdx.x * 256 + threadIdx.x;
  if (i < n) out[i] = f32_to_bf16(in[i]);
}

// W [k][n] fp32 -> WT [n][k] bf16 (coalesced writes)
__global__ void transpose_kernel(const float* __restrict__ W, ushort_t* __restrict__ WT) {
  int i = blockIdx.x * 256 + threadIdx.x;
  if (i >= DIM * DIM) return;
  int nrow = i / DIM;
  int k = i - nrow * DIM;
  WT[i] = f32_to_bf16(W[k * DIM + nrow]);
}

// ---------------- bf16 MFMA GEMM: C[M,768] = A[M,768] x (Bt[768,768])^T ----------------
// A row-major (k contig), Bt is W^T stored [n][k] (k contig), C fp32.
__global__ __launch_bounds__(256)
void gemm_kernel(const ushort_t* __restrict__ A, const ushort_t* __restrict__ Bt,
                 float* __restrict__ C, int M) {
  const int K = DIM;
  __shared__ __align__(16) ushort_t As[128 * 40];   // 128 rows x 32 k, stride 40 (pad)
  __shared__ __align__(16) ushort_t Bs[128 * 40];
  int tid = threadIdx.x;
  int m0 = blockIdx.x * 128, n0 = blockIdx.y * 128;
  int wave = tid >> 6, lane = tid & 63;
  int wm = (wave & 1) * 64, wn = (wave >> 1) * 64;
  int quad = lane >> 4, l16 = lane & 15;

  floatx4 acc[4][4];
  const floatx4 fzero = {0.f, 0.f, 0.f, 0.f};
#pragma unroll
  for (int i = 0; i < 4; ++i)
#pragma unroll
    for (int j = 0; j < 4; ++j) acc[i][j] = fzero;

  int r0 = tid >> 2;          // 0..63
  int ko = (tid & 3) * 8;     // 0,8,16,24 (bf16 elems)
  int r1 = r0 + 64;

  for (int k0 = 0; k0 < K; k0 += 32) {
    uint4 va0 = make_uint4(0, 0, 0, 0), va1 = make_uint4(0, 0, 0, 0);
    int gr0 = m0 + r0, gr1 = m0 + r1;
    if (gr0 < M) va0 = *(const uint4*)(A + (size_t)gr0 * K + k0 + ko);
    if (gr1 < M) va1 = *(const uint4*)(A + (size_t)gr1 * K + k0 + ko);
    uint4 vb0 = *(const uint4*)(Bt + (size_t)(n0 + r0) * K + k0 + ko);
    uint4 vb1 = *(const uint4*)(Bt + (size_t)(n0 + r1) * K + k0 + ko);
    *(uint4*)(&As[r0 * 40 + ko]) = va0;
    *(uint4*)(&As[r1 * 40 + ko]) = va1;
    *(uint4*)(&Bs[r0 * 40 + ko]) = vb0;
    *(uint4*)(&Bs[r1 * 40 + ko]) = vb1;
    __syncthreads();

    short8 af[4], bf[4];
#pragma unroll
    for (int i = 0; i < 4; ++i) {
      af[i] = *(const short8*)(&As[(wm + i * 16 + l16) * 40 + quad * 8]);
      bf[i] = *(const short8*)(&Bs[(wn + i * 16 + l16) * 40 + quad * 8]);
    }
#pragma unroll
    for (int i = 0; i < 4; ++i)
#pragma unroll
      for (int j = 0; j < 4; ++j)
        acc[i][j] = __builtin_amdgcn_mfma_f32_16x16x32_bf16(af[i], bf[j], acc[i][j], 0, 0, 0);
    __syncthreads();
  }

#pragma unroll
  for (int i = 0; i < 4; ++i) {
    int rb = m0 + wm + i * 16 + quad * 4;
#pragma unroll
    for (int j = 0; j < 4; ++j) {
      int c = n0 + wn + j * 16 + l16;
#pragma unroll
      for (int r = 0; r < 4; ++r) {
        int row = rb + r;
        if (row < M) C[(size_t)row * DIM + c] = acc[i][j][r];
      }
    }
  }
}

// ---------------- per-node attention coefficients: a_s = h . att_s, a_d = h . att_d ----
__global__ __launch_bounds__(256)
void attcoef_kernel(const float* __restrict__ h, const float* __restrict__ att_s,
                    const float* __restrict__ att_d, float* __restrict__ a_s,
                    float* __restrict__ a_d, int N) {
  int wave = threadIdx.x >> 6, lane = threadIdx.x & 63;
  int node = blockIdx.x * 4 + wave;
  if (node >= N) return;
  const float4* hr = (const float4*)(h + (size_t)node * DIM);
  const float4* s4 = (const float4*)att_s;
  const float4* d4 = (const float4*)att_d;
  float ss = 0.f, sd = 0.f;
#pragma unroll
  for (int j = 0; j < 3; ++j) {
    int idx = j * 64 + lane;
    float4 hv = hr[idx], sv = s4[idx], dv = d4[idx];
    ss += hv.x * sv.x + hv.y * sv.y + hv.z * sv.z + hv.w * sv.w;
    sd += hv.x * dv.x + hv.y * dv.y + hv.z * dv.z + hv.w * dv.w;
  }
#pragma unroll
  for (int off = 32; off > 0; off >>= 1) {
    ss += __shfl_xor(ss, off, 64);
    sd += __shfl_xor(sd, off, 64);
  }
  if (lane == 0) { a_s[node] = ss; a_d[node] = sd; }
}

// ---------------- segment softmax + weighted gather-sum, one block per dst node -------
__global__ __launch_bounds__(256)
void aggregate_kernel(const float* __restrict__ h, const float* __restrict__ a_s,
                      const float* __restrict__ a_d, const int* __restrict__ rowstart,
                      const int* __restrict__ col, const float* __restrict__ bias,
                      float* __restrict__ out_f32, ushort_t* __restrict__ out_bf16,
                      int relu_mode) {
  __shared__ float red[256];
  __shared__ float w_sh[256];
  __shared__ int s_sh[256];
  int i = blockIdx.x;
  int tid = threadIdx.x;
  int start = rowstart[i], end = rowstart[i + 1];
  float ad = a_d[i];

  // phase 1: segment max of leaky_relu(a_s[src] + a_d[dst])
  float lmax = -3.4e38f;
  for (int e = start + tid; e < end; e += 256) {
    float v = a_s[col[e]] + ad;
    v = (v > 0.f) ? v : NEG_SLOPE * v;
    lmax = fmaxf(lmax, v);
  }
  red[tid] = lmax;
  __syncthreads();
  for (int s = 128; s > 0; s >>= 1) {
    if (tid < s) red[tid] = fmaxf(red[tid], red[tid + s]);
    __syncthreads();
  }
  float m = red[0];
  __syncthreads();

  // phase 2: segment sum of exp
  float lsum = 0.f;
  for (int e = start + tid; e < end; e += 256) {
    float v = a_s[col[e]] + ad;
    v = (v > 0.f) ? v : NEG_SLOPE * v;
    lsum += __expf(v - m);
  }
  red[tid] = lsum;
  __syncthreads();
  for (int s = 128; s > 0; s >>= 1) {
    if (tid < s) red[tid] += red[tid + s];
    __syncthreads();
  }
  float inv = 1.f / red[0];
  __syncthreads();

  // phase 3: out[i,:] = sum_e alpha_e * h[src_e,:]  (each thread owns 3 columns)
  float acc0 = 0.f, acc1 = 0.f, acc2 = 0.f;
  int c0 = tid, c1 = tid + 256, c2 = tid + 512;
  for (int base = start; base < end; base += 256) {
    int idx = base + tid;
    if (idx < end) {
      int s = col[idx];
      float v = a_s[s] + ad;
      v = (v > 0.f) ? v : NEG_SLOPE * v;
      w_sh[tid] = __expf(v - m) * inv;
      s_sh[tid] = s;
    }
    __syncthreads();
    int cnt = min(256, end - base);
    for (int j = 0; j < cnt; ++j) {
      const float* hr = h + (size_t)s_sh[j] * DIM;
      float w = w_sh[j];
      acc0 = fmaf(w, hr[c0], acc0);
      acc1 = fmaf(w, hr[c1], acc1);
      acc2 = fmaf(w, hr[c2], acc2);
    }
    __syncthreads();
  }
  float o0 = acc0 + bias[c0];
  float o1 = acc1 + bias[c1];
  float o2 = acc2 + bias[c2];
  size_t ob = (size_t)i * DIM;
  if (relu_mode) {
    o0 = fmaxf(o0, 0.f); o1 = fmaxf(o1, 0.f); o2 = fmaxf(o2, 0.f);
    out_bf16[ob + c0] = f32_to_bf16(o0);
    out_bf16[ob + c1] = f32_to_bf16(o1);
    out_bf16[ob + c2] = f32_to_bf16(o2);
  } else {
    out_f32[ob + c0] = o0;
    out_f32[ob + c1] = o1;
    out_f32[ob + c2] = o2;
  }
}

extern "C" void kernel_launch(void* const* d_in, const int* in_sizes, int n_in,
                              void* d_out, int out_size, void* d_ws, size_t ws_size,
                              hipStream_t stream) {
  const float* x   = (const float*)d_in[0];
  const int*   ei  = (const int*)d_in[1];
  const float* W1  = (const float*)d_in[2];
  const float* as1 = (const float*)d_in[3];
  const float* ad1 = (const float*)d_in[4];
  const float* b1  = (const float*)d_in[5];
  const float* W2  = (const float*)d_in[6];
  const float* as2 = (const float*)d_in[7];
  const float* ad2 = (const float*)d_in[8];
  const float* b2  = (const float*)d_in[9];

  const int N = in_sizes[0] / DIM;   // 10000
  const int E = in_sizes[1] / 2;     // 100000
  const int Etot = E + N;

  char* p = (char*)d_ws;
  auto alloc = [&](size_t bytes) {
    char* q = p;
    p += (bytes + 255) & ~(size_t)255;
    return q;
  };
  float*    h      = (float*)alloc((size_t)N * DIM * 4);
  ushort_t* xb     = (ushort_t*)alloc((size_t)N * DIM * 2);
  ushort_t* wT     = (ushort_t*)alloc((size_t)DIM * DIM * 2);
  float*    a_s    = (float*)alloc((size_t)N * 4);
  float*    a_d    = (float*)alloc((size_t)N * 4);
  int*      deg    = (int*)alloc((size_t)N * 4);
  int*      rowst  = (int*)alloc((size_t)(N + 1) * 4);
  int*      cursor = (int*)alloc((size_t)N * 4);
  int*      col    = (int*)alloc((size_t)Etot * 4);

  // CSR build
  hipMemsetAsync(deg, 0, (size_t)N * 4, stream);
  hist_kernel<<<(Etot + 255) / 256, 256, 0, stream>>>(ei, deg, E, Etot);
  scan_kernel<<<1, 256, 0, stream>>>(deg, rowst, cursor, N, Etot);
  fill_kernel<<<(Etot + 255) / 256, 256, 0, stream>>>(ei, cursor, col, E, Etot);

  dim3 ggrid((N + 127) / 128, DIM / 128);

  // Layer 1
  cast_kernel<<<(N * DIM + 255) / 256, 256, 0, stream>>>(x, xb, N * DIM);
  transpose_kernel<<<(DIM * DIM + 255) / 256, 256, 0, stream>>>(W1, wT);
  gemm_kernel<<<ggrid, 256, 0, stream>>>(xb, wT, h, N);
  attcoef_kernel<<<(N + 3) / 4, 256, 0, stream>>>(h, as1, ad1, a_s, a_d, N);
  aggregate_kernel<<<N, 256, 0, stream>>>(h, a_s, a_d, rowst, col, b1,
                                          nullptr, xb, 1);  // relu -> bf16 (layer2 input)

  // Layer 2
  transpose_kernel<<<(DIM * DIM + 255) / 256, 256, 0, stream>>>(W2, wT);
  gemm_kernel<<<ggrid, 256, 0, stream>>>(xb, wT, h, N);
  attcoef_kernel<<<(N + 3) / 4, 256, 0, stream>>>(h, as2, ad2, a_s, a_d, N);
  aggregate_kernel<<<N, 256, 0, stream>>>(h, a_s, a_d, rowst, col, b2,
                                          (float*)d_out, nullptr, 0);
}

// Round 2
// 284.220 us; speedup vs baseline: 1.1282x; 1.1282x over previous
//
#include <hip/hip_runtime.h>

#define DIM 768
#define NEG_SLOPE 0.2f

typedef unsigned short ushort_t;
typedef short short8 __attribute__((ext_vector_type(8)));
typedef float floatx4 __attribute__((ext_vector_type(4)));

__device__ __forceinline__ ushort_t f32_to_bf16(float f) {
  unsigned int b = __float_as_uint(f);
  b += 0x7FFFu + ((b >> 16) & 1u);   // RNE
  return (ushort_t)(b >> 16);
}
__device__ __forceinline__ float bf16_to_f32(ushort_t u) {
  return __uint_as_float(((unsigned int)u) << 16);
}

// async global->LDS, 16B per lane. LDS dest = wave-uniform base + lane*16.
__device__ __forceinline__ void gl2lds16(const ushort_t* g, ushort_t* l) {
  __builtin_amdgcn_global_load_lds(
      (const __attribute__((address_space(1))) void*)g,
      (__attribute__((address_space(3))) void*)l, 16, 0, 0);
}

// ---------------- CSR build (by destination, self-loops appended) ----------------
__global__ void hist_kernel(const int* __restrict__ ei, int* __restrict__ deg,
                            int E, int Etot) {
  int e = blockIdx.x * 256 + threadIdx.x;
  if (e >= Etot) return;
  int d = (e < E) ? ei[E + e] : (e - E);
  atomicAdd(&deg[d], 1);
}

__global__ void scan_kernel(const int* __restrict__ deg, int* __restrict__ rowstart,
                            int* __restrict__ cursor, int n, int etot) {
  __shared__ int part[256];
  int tid = threadIdx.x;
  int chunk = (n + 255) / 256;
  int lo = tid * chunk;
  int hi = min(lo + chunk, n);
  int s = 0;
  for (int i = lo; i < hi; ++i) s += deg[i];
  part[tid] = s;
  __syncthreads();
  for (int off = 1; off < 256; off <<= 1) {
    int v = part[tid];
    int add = (tid >= off) ? part[tid - off] : 0;
    __syncthreads();
    part[tid] = v + add;
    __syncthreads();
  }
  int run = (tid == 0) ? 0 : part[tid - 1];
  for (int i = lo; i < hi; ++i) {
    rowstart[i] = run;
    cursor[i] = run;
    run += deg[i];
  }
  if (tid == 0) rowstart[n] = etot;
}

__global__ void fill_kernel(const int* __restrict__ ei, int* __restrict__ cursor,
                            int* __restrict__ col, int E, int Etot) {
  int e = blockIdx.x * 256 + threadIdx.x;
  if (e >= Etot) return;
  int s, d;
  if (e < E) { s = ei[e]; d = ei[E + e]; }
  else       { s = e - E; d = e - E; }
  int pos = atomicAdd(&cursor[d], 1);
  col[pos] = s;
}

// ---------------- fp32 -> bf16 cast ----------------
__global__ void cast_kernel(const float* __restrict__ in, ushort_t* __restrict__ out, int n) {
  int i = blockIdx.x * 256 + threadIdx.x;
  if (i < n) out[i] = f32_to_bf16(in[i]);
}

// W [k][n] fp32 -> WT [n][k] bf16 (coalesced writes)
__global__ void transpose_kernel(const float* __restrict__ W, ushort_t* __restrict__ WT) {
  int i = blockIdx.x * 256 + threadIdx.x;
  if (i >= DIM * DIM) return;
  int nrow = i / DIM;
  int k = i - nrow * DIM;
  WT[i] = f32_to_bf16(W[k * DIM + nrow]);
}

// ---------------- bf16 MFMA GEMM with global_load_lds staging --------------------
// C[M,768] = A[M,768] x (Bt)^T; A row-major bf16, Bt = W^T [n][k] bf16.
// Writes Hb (bf16 h) and fused a_s/a_d partials (atomicAdd, pre-zeroed).
// LDS: unpadded [128][32] per tile; chunk-XOR swizzle f(r)=(r+(r>>2))&3 so the
// b128 fragment reads are 2-way-bank-aliased (free) instead of 4/8-way.
__global__ __launch_bounds__(256)
void gemm_kernel(const ushort_t* __restrict__ A, const ushort_t* __restrict__ Bt,
                 const float* __restrict__ att_s, const float* __restrict__ att_d,
                 float* __restrict__ a_s, float* __restrict__ a_d,
                 ushort_t* __restrict__ Hb, int M) {
  const int K = DIM;
  __shared__ __align__(16) ushort_t As[128 * 32];
  __shared__ __align__(16) ushort_t Bs[128 * 32];
  int tid = threadIdx.x;
  int m0 = blockIdx.x * 128, n0 = blockIdx.y * 128;
  int wave = tid >> 6, lane = tid & 63;
  int wm = (wave & 1) * 64, wn = (wave >> 1) * 64;
  int quad = lane >> 4, l16 = lane & 15;

  floatx4 acc[4][4];
  const floatx4 fzero = {0.f, 0.f, 0.f, 0.f};
#pragma unroll
  for (int i = 0; i < 4; ++i)
#pragma unroll
    for (int j = 0; j < 4; ++j) acc[i][j] = fzero;

  int r0 = tid >> 2, c0 = tid & 3;
  int r1 = r0 + 64;
  int kc0 = ((c0 ^ ((r0 + (r0 >> 2)) & 3))) * 8;  // swizzled global chunk for slot (r0,c0)
  int kc1 = ((c0 ^ ((r1 + (r1 >> 2)) & 3))) * 8;

  const ushort_t* gA0 = A + (size_t)min(m0 + r0, M - 1) * K + kc0;
  const ushort_t* gA1 = A + (size_t)min(m0 + r1, M - 1) * K + kc1;
  const ushort_t* gB0 = Bt + (size_t)(n0 + r0) * K + kc0;
  const ushort_t* gB1 = Bt + (size_t)(n0 + r1) * K + kc1;
  ushort_t* lA0 = As + wave * 512;          // wave-uniform bases (lane*16B implicit)
  ushort_t* lA1 = As + 2048 + wave * 512;
  ushort_t* lB0 = Bs + wave * 512;
  ushort_t* lB1 = Bs + 2048 + wave * 512;

  for (int k0 = 0; k0 < K; k0 += 32) {
    gl2lds16(gA0 + k0, lA0);
    gl2lds16(gA1 + k0, lA1);
    gl2lds16(gB0 + k0, lB0);
    gl2lds16(gB1 + k0, lB1);
    __syncthreads();   // drains vmcnt for all waves' loads + barrier

    short8 af[4], bfr[4];
#pragma unroll
    for (int i = 0; i < 4; ++i) {
      int ra = wm + i * 16 + l16;
      int qa = quad ^ ((ra + (ra >> 2)) & 3);
      af[i] = *(const short8*)(As + ra * 32 + qa * 8);
      int rb = wn + i * 16 + l16;
      int qb = quad ^ ((rb + (rb >> 2)) & 3);
      bfr[i] = *(const short8*)(Bs + rb * 32 + qb * 8);
    }
#pragma unroll
    for (int i = 0; i < 4; ++i)
#pragma unroll
      for (int j = 0; j < 4; ++j)
        acc[i][j] = __builtin_amdgcn_mfma_f32_16x16x32_bf16(af[i], bfr[j], acc[i][j], 0, 0, 0);
    __syncthreads();   // before next iter overwrites LDS
  }

  // att vector slices for this block's 4 column groups
  float avs[4], avd[4];
#pragma unroll
  for (int j = 0; j < 4; ++j) {
    int c = n0 + wn + j * 16 + l16;
    avs[j] = att_s[c];
    avd[j] = att_d[c];
  }

  // epilogue: bf16 store + fused a_s/a_d partial (reduce over l16, atomic per row)
#pragma unroll
  for (int i = 0; i < 4; ++i) {
#pragma unroll
    for (int r = 0; r < 4; ++r) {
      int row = m0 + wm + i * 16 + quad * 4 + r;
      bool valid = row < M;
      float pvs = 0.f, pvd = 0.f;
#pragma unroll
      for (int j = 0; j < 4; ++j) {
        float v = acc[i][j][r];
        if (valid) Hb[(size_t)row * DIM + n0 + wn + j * 16 + l16] = f32_to_bf16(v);
        pvs = fmaf(v, avs[j], pvs);
        pvd = fmaf(v, avd[j], pvd);
      }
#pragma unroll
      for (int off = 1; off < 16; off <<= 1) {
        pvs += __shfl_xor(pvs, off, 64);
        pvd += __shfl_xor(pvd, off, 64);
      }
      if (valid && l16 == 0) {
        atomicAdd(a_s + row, pvs);
        atomicAdd(a_d + row, pvd);
      }
    }
  }
}

// ---------------- segment softmax + weighted gather-sum (bf16 h), 1 block/node -------
__global__ __launch_bounds__(256)
void aggregate_kernel(const ushort_t* __restrict__ h, const float* __restrict__ a_s,
                      const float* __restrict__ a_d, const int* __restrict__ rowstart,
                      const int* __restrict__ col, const float* __restrict__ bias,
                      float* __restrict__ out_f32, ushort_t* __restrict__ out_bf16,
                      int relu_mode) {
  __shared__ float red[256];
  __shared__ float w_sh[256];
  __shared__ int s_sh[256];
  int i = blockIdx.x;
  int tid = threadIdx.x;
  int start = rowstart[i], end = rowstart[i + 1];
  float ad = a_d[i];

  // phase 1: segment max of leaky_relu(a_s[src] + a_d[dst])
  float lmax = -3.4e38f;
  for (int e = start + tid; e < end; e += 256) {
    float v = a_s[col[e]] + ad;
    v = (v > 0.f) ? v : NEG_SLOPE * v;
    lmax = fmaxf(lmax, v);
  }
  red[tid] = lmax;
  __syncthreads();
  for (int s = 128; s > 0; s >>= 1) {
    if (tid < s) red[tid] = fmaxf(red[tid], red[tid + s]);
    __syncthreads();
  }
  float m = red[0];
  __syncthreads();

  // phase 2: segment sum of exp
  float lsum = 0.f;
  for (int e = start + tid; e < end; e += 256) {
    float v = a_s[col[e]] + ad;
    v = (v > 0.f) ? v : NEG_SLOPE * v;
    lsum += __expf(v - m);
  }
  red[tid] = lsum;
  __syncthreads();
  for (int s = 128; s > 0; s >>= 1) {
    if (tid < s) red[tid] += red[tid + s];
    __syncthreads();
  }
  float inv = 1.f / red[0];
  __syncthreads();

  // phase 3: out[i,:] = sum_e alpha_e * h[src_e,:]  (3 cols/thread, bf16 gather)
  float acc0 = 0.f, acc1 = 0.f, acc2 = 0.f;
  int c0 = tid, c1 = tid + 256, c2 = tid + 512;
  for (int base = start; base < end; base += 256) {
    int idx = base + tid;
    if (idx < end) {
      int s = col[idx];
      float v = a_s[s] + ad;
      v = (v > 0.f) ? v : NEG_SLOPE * v;
      w_sh[tid] = __expf(v - m) * inv;
      s_sh[tid] = s;
    }
    __syncthreads();
    int cnt = min(256, end - base);
    for (int j = 0; j < cnt; ++j) {
      const ushort_t* hr = h + (size_t)s_sh[j] * DIM;
      float w = w_sh[j];
      acc0 = fmaf(w, bf16_to_f32(hr[c0]), acc0);
      acc1 = fmaf(w, bf16_to_f32(hr[c1]), acc1);
      acc2 = fmaf(w, bf16_to_f32(hr[c2]), acc2);
    }
    __syncthreads();
  }
  float o0 = acc0 + bias[c0];
  float o1 = acc1 + bias[c1];
  float o2 = acc2 + bias[c2];
  size_t ob = (size_t)i * DIM;
  if (relu_mode) {
    o0 = fmaxf(o0, 0.f); o1 = fmaxf(o1, 0.f); o2 = fmaxf(o2, 0.f);
    out_bf16[ob + c0] = f32_to_bf16(o0);
    out_bf16[ob + c1] = f32_to_bf16(o1);
    out_bf16[ob + c2] = f32_to_bf16(o2);
  } else {
    out_f32[ob + c0] = o0;
    out_f32[ob + c1] = o1;
    out_f32[ob + c2] = o2;
  }
}

extern "C" void kernel_launch(void* const* d_in, const int* in_sizes, int n_in,
                              void* d_out, int out_size, void* d_ws, size_t ws_size,
                              hipStream_t stream) {
  const float* x   = (const float*)d_in[0];
  const int*   ei  = (const int*)d_in[1];
  const float* W1  = (const float*)d_in[2];
  const float* as1 = (const float*)d_in[3];
  const float* ad1 = (const float*)d_in[4];
  const float* b1  = (const float*)d_in[5];
  const float* W2  = (const float*)d_in[6];
  const float* as2 = (const float*)d_in[7];
  const float* ad2 = (const float*)d_in[8];
  const float* b2  = (const float*)d_in[9];

  const int N = in_sizes[0] / DIM;   // 10000
  const int E = in_sizes[1] / 2;     // 100000
  const int Etot = E + N;

  char* p = (char*)d_ws;
  auto alloc = [&](size_t bytes) {
    char* q = p;
    p += (bytes + 255) & ~(size_t)255;
    return q;
  };
  ushort_t* Hb     = (ushort_t*)alloc((size_t)N * DIM * 2);  // bf16 h
  ushort_t* xb     = (ushort_t*)alloc((size_t)N * DIM * 2);  // bf16 layer input
  ushort_t* wT     = (ushort_t*)alloc((size_t)DIM * DIM * 2);
  float*    a_sd   = (float*)alloc((size_t)2 * N * 4);       // a_s | a_d contiguous
  float*    a_s    = a_sd;
  float*    a_d    = a_sd + N;
  int*      deg    = (int*)alloc((size_t)N * 4);
  int*      rowst  = (int*)alloc((size_t)(N + 1) * 4);
  int*      cursor = (int*)alloc((size_t)N * 4);
  int*      col    = (int*)alloc((size_t)Etot * 4);

  // CSR build
  hipMemsetAsync(deg, 0, (size_t)N * 4, stream);
  hist_kernel<<<(Etot + 255) / 256, 256, 0, stream>>>(ei, deg, E, Etot);
  scan_kernel<<<1, 256, 0, stream>>>(deg, rowst, cursor, N, Etot);
  fill_kernel<<<(Etot + 255) / 256, 256, 0, stream>>>(ei, cursor, col, E, Etot);

  dim3 ggrid((N + 127) / 128, DIM / 128);

  // Layer 1
  cast_kernel<<<(N * DIM + 255) / 256, 256, 0, stream>>>(x, xb, N * DIM);
  transpose_kernel<<<(DIM * DIM + 255) / 256, 256, 0, stream>>>(W1, wT);
  hipMemsetAsync(a_sd, 0, (size_t)2 * N * 4, stream);
  gemm_kernel<<<ggrid, 256, 0, stream>>>(xb, wT, as1, ad1, a_s, a_d, Hb, N);
  aggregate_kernel<<<N, 256, 0, stream>>>(Hb, a_s, a_d, rowst, col, b1,
                                          nullptr, xb, 1);  // relu -> bf16 (layer2 input)

  // Layer 2
  transpose_kernel<<<(DIM * DIM + 255) / 256, 256, 0, stream>>>(W2, wT);
  hipMemsetAsync(a_sd, 0, (size_t)2 * N * 4, stream);
  gemm_kernel<<<ggrid, 256, 0, stream>>>(xb, wT, as2, ad2, a_s, a_d, Hb, N);
  aggregate_kernel<<<N, 256, 0, stream>>>(Hb, a_s, a_d, rowst, col, b2,
                                          (float*)d_out, nullptr, 0);
}

// Round 3
// 244.027 us; speedup vs baseline: 1.3140x; 1.1647x over previous
//
#include <hip/hip_runtime.h>

#define DIM 768
#define NEG_SLOPE 0.2f

typedef unsigned short ushort_t;
typedef short short8 __attribute__((ext_vector_type(8)));
typedef float floatx4 __attribute__((ext_vector_type(4)));

__device__ __forceinline__ ushort_t f32_to_bf16(float f) {
  unsigned int b = __float_as_uint(f);
  b += 0x7FFFu + ((b >> 16) & 1u);   // RNE
  return (ushort_t)(b >> 16);
}
__device__ __forceinline__ float bf16_to_f32(ushort_t u) {
  return __uint_as_float(((unsigned int)u) << 16);
}

// async global->LDS, 16B per lane. LDS dest = wave-uniform base + lane*16.
__device__ __forceinline__ void gl2lds16(const ushort_t* g, ushort_t* l) {
  __builtin_amdgcn_global_load_lds(
      (const __attribute__((address_space(1))) void*)g,
      (__attribute__((address_space(3))) void*)l, 16, 0, 0);
}

// ---------------- CSR build (by destination, self-loops appended) ----------------
__global__ void hist_kernel(const int* __restrict__ ei, int* __restrict__ deg,
                            int E, int Etot) {
  int e = blockIdx.x * 256 + threadIdx.x;
  if (e >= Etot) return;
  int d = (e < E) ? ei[E + e] : (e - E);
  atomicAdd(&deg[d], 1);
}

// single-block scan; deg staged in LDS (coalesced global I/O); odd chunk stride
// (41 for n=10000) keeps the blocked LDS walks at 2-way bank alias (free).
__global__ __launch_bounds__(256)
void scan_kernel(const int* __restrict__ deg, int* __restrict__ rowstart,
                 int* __restrict__ cursor, int n, int etot) {
  __shared__ int sdeg[10240];
  __shared__ int part[256];
  int tid = threadIdx.x;
  for (int i = tid; i < n; i += 256) sdeg[i] = deg[i];
  __syncthreads();
  int chunk = ((n + 255) / 256) | 1;
  int lo = min(tid * chunk, n);
  int hi = min(lo + chunk, n);
  int s = 0;
  for (int i = lo; i < hi; ++i) s += sdeg[i];
  part[tid] = s;
  __syncthreads();
  for (int off = 1; off < 256; off <<= 1) {
    int v = part[tid];
    int add = (tid >= off) ? part[tid - off] : 0;
    __syncthreads();
    part[tid] = v + add;
    __syncthreads();
  }
  int run = (tid == 0) ? 0 : part[tid - 1];
  for (int i = lo; i < hi; ++i) {
    int d = sdeg[i];
    sdeg[i] = run;
    run += d;
  }
  __syncthreads();
  for (int i = tid; i < n; i += 256) {
    int v = sdeg[i];
    rowstart[i] = v;
    cursor[i] = v;
  }
  if (tid == 0) rowstart[n] = etot;
}

__global__ void fill_kernel(const int* __restrict__ ei, int* __restrict__ cursor,
                            int* __restrict__ col, int E, int Etot) {
  int e = blockIdx.x * 256 + threadIdx.x;
  if (e >= Etot) return;
  int s, d;
  if (e < E) { s = ei[e]; d = ei[E + e]; }
  else       { s = e - E; d = e - E; }
  int pos = atomicAdd(&cursor[d], 1);
  col[pos] = s;
}

// ---------------- fused prep: x->bf16 (float4) + both W transposes ----------------
__global__ __launch_bounds__(256)
void prep_kernel(const float* __restrict__ x, ushort_t* __restrict__ xb, int n4,
                 const float* __restrict__ W1, ushort_t* __restrict__ wT1,
                 const float* __restrict__ W2, ushort_t* __restrict__ wT2) {
  int i = blockIdx.x * 256 + threadIdx.x;
  if (i < n4) {
    float4 v = ((const float4*)x)[i];
    ushort4 o;
    o.x = f32_to_bf16(v.x); o.y = f32_to_bf16(v.y);
    o.z = f32_to_bf16(v.z); o.w = f32_to_bf16(v.w);
    ((ushort4*)xb)[i] = o;
  }
  if (i < DIM * DIM) {
    int nrow = i / DIM;
    int k = i - nrow * DIM;
    wT1[i] = f32_to_bf16(W1[k * DIM + nrow]);
    wT2[i] = f32_to_bf16(W2[k * DIM + nrow]);
  }
}

// ---------------- bf16 MFMA GEMM with global_load_lds staging --------------------
// C[M,768] = A[M,768] x (Bt)^T; writes Hb (bf16) + fused a_s/a_d (atomic, pre-zeroed).
__global__ __launch_bounds__(256)
void gemm_kernel(const ushort_t* __restrict__ A, const ushort_t* __restrict__ Bt,
                 const float* __restrict__ att_s, const float* __restrict__ att_d,
                 float* __restrict__ a_s, float* __restrict__ a_d,
                 ushort_t* __restrict__ Hb, int M) {
  const int K = DIM;
  __shared__ __align__(16) ushort_t As[128 * 32];
  __shared__ __align__(16) ushort_t Bs[128 * 32];
  int tid = threadIdx.x;
  int m0 = blockIdx.x * 128, n0 = blockIdx.y * 128;
  int wave = tid >> 6, lane = tid & 63;
  int wm = (wave & 1) * 64, wn = (wave >> 1) * 64;
  int quad = lane >> 4, l16 = lane & 15;

  floatx4 acc[4][4];
  const floatx4 fzero = {0.f, 0.f, 0.f, 0.f};
#pragma unroll
  for (int i = 0; i < 4; ++i)
#pragma unroll
    for (int j = 0; j < 4; ++j) acc[i][j] = fzero;

  int r0 = tid >> 2, c0 = tid & 3;
  int r1 = r0 + 64;
  int kc0 = ((c0 ^ ((r0 + (r0 >> 2)) & 3))) * 8;
  int kc1 = ((c0 ^ ((r1 + (r1 >> 2)) & 3))) * 8;

  const ushort_t* gA0 = A + (size_t)min(m0 + r0, M - 1) * K + kc0;
  const ushort_t* gA1 = A + (size_t)min(m0 + r1, M - 1) * K + kc1;
  const ushort_t* gB0 = Bt + (size_t)(n0 + r0) * K + kc0;
  const ushort_t* gB1 = Bt + (size_t)(n0 + r1) * K + kc1;
  ushort_t* lA0 = As + wave * 512;
  ushort_t* lA1 = As + 2048 + wave * 512;
  ushort_t* lB0 = Bs + wave * 512;
  ushort_t* lB1 = Bs + 2048 + wave * 512;

  for (int k0 = 0; k0 < K; k0 += 32) {
    gl2lds16(gA0 + k0, lA0);
    gl2lds16(gA1 + k0, lA1);
    gl2lds16(gB0 + k0, lB0);
    gl2lds16(gB1 + k0, lB1);
    __syncthreads();

    short8 af[4], bfr[4];
#pragma unroll
    for (int i = 0; i < 4; ++i) {
      int ra = wm + i * 16 + l16;
      int qa = quad ^ ((ra + (ra >> 2)) & 3);
      af[i] = *(const short8*)(As + ra * 32 + qa * 8);
      int rb = wn + i * 16 + l16;
      int qb = quad ^ ((rb + (rb >> 2)) & 3);
      bfr[i] = *(const short8*)(Bs + rb * 32 + qb * 8);
    }
#pragma unroll
    for (int i = 0; i < 4; ++i)
#pragma unroll
      for (int j = 0; j < 4; ++j)
        acc[i][j] = __builtin_amdgcn_mfma_f32_16x16x32_bf16(af[i], bfr[j], acc[i][j], 0, 0, 0);
    __syncthreads();
  }

  float avs[4], avd[4];
#pragma unroll
  for (int j = 0; j < 4; ++j) {
    int c = n0 + wn + j * 16 + l16;
    avs[j] = att_s[c];
    avd[j] = att_d[c];
  }

#pragma unroll
  for (int i = 0; i < 4; ++i) {
#pragma unroll
    for (int r = 0; r < 4; ++r) {
      int row = m0 + wm + i * 16 + quad * 4 + r;
      bool valid = row < M;
      float pvs = 0.f, pvd = 0.f;
#pragma unroll
      for (int j = 0; j < 4; ++j) {
        float v = acc[i][j][r];
        if (valid) Hb[(size_t)row * DIM + n0 + wn + j * 16 + l16] = f32_to_bf16(v);
        pvs = fmaf(v, avs[j], pvs);
        pvd = fmaf(v, avd[j], pvd);
      }
#pragma unroll
      for (int off = 1; off < 16; off <<= 1) {
        pvs += __shfl_xor(pvs, off, 64);
        pvd += __shfl_xor(pvd, off, 64);
      }
      if (valid && l16 == 0) {
        atomicAdd(a_s + row, pvs);
        atomicAdd(a_d + row, pvd);
      }
    }
  }
}

// ---------------- wave-per-node segment softmax + gather-sum (bf16 h) ----------------
// 4 nodes/block (1/wave). Lanes parallel over edges for softmax (shuffle reduce),
// per-edge (alpha, src) broadcast via shfl; full 768-col row as 3x ushort4/lane.
__global__ __launch_bounds__(256)
void aggregate_kernel(const ushort_t* __restrict__ h, const float* __restrict__ a_s,
                      const float* __restrict__ a_d, const int* __restrict__ rowstart,
                      const int* __restrict__ col, const float* __restrict__ bias,
                      float* __restrict__ out_f32, ushort_t* __restrict__ out_bf16,
                      int relu_mode, int N) {
  int wave = threadIdx.x >> 6, lane = threadIdx.x & 63;
  int node = blockIdx.x * 4 + wave;
  if (node >= N) return;
  int start = rowstart[node], end = rowstart[node + 1];
  float ad = a_d[node];

  // pass 1: segment max of leaky_relu(a_s[src] + a_d[dst])
  float vmax = -3.4e38f;
  for (int e = start + lane; e < end; e += 64) {
    float v = a_s[col[e]] + ad;
    v = (v > 0.f) ? v : NEG_SLOPE * v;
    vmax = fmaxf(vmax, v);
  }
#pragma unroll
  for (int off = 32; off > 0; off >>= 1) vmax = fmaxf(vmax, __shfl_xor(vmax, off, 64));

  // pass 2: segment sum of exp
  float ssum = 0.f;
  for (int e = start + lane; e < end; e += 64) {
    float v = a_s[col[e]] + ad;
    v = (v > 0.f) ? v : NEG_SLOPE * v;
    ssum += __expf(v - vmax);
  }
#pragma unroll
  for (int off = 32; off > 0; off >>= 1) ssum += __shfl_xor(ssum, off, 64);
  float inv = 1.f / ssum;

  // pass 3: weighted gather
  float acc[3][4];
#pragma unroll
  for (int q = 0; q < 3; ++q)
#pragma unroll
    for (int k = 0; k < 4; ++k) acc[q][k] = 0.f;

  for (int base = start; base < end; base += 64) {
    int e = base + lane;
    float al = 0.f;
    int sc = 0;
    if (e < end) {
      sc = col[e];
      float v = a_s[sc] + ad;
      v = (v > 0.f) ? v : NEG_SLOPE * v;
      al = __expf(v - vmax) * inv;
    }
    int cnt = min(64, end - base);
    for (int j = 0; j < cnt; ++j) {
      float w = __shfl(al, j, 64);
      int s = __shfl(sc, j, 64);
      const ushort_t* hr = h + (size_t)s * DIM;
#pragma unroll
      for (int q = 0; q < 3; ++q) {
        ushort4 u = *(const ushort4*)(hr + 4 * (lane + 64 * q));
        acc[q][0] = fmaf(w, bf16_to_f32(u.x), acc[q][0]);
        acc[q][1] = fmaf(w, bf16_to_f32(u.y), acc[q][1]);
        acc[q][2] = fmaf(w, bf16_to_f32(u.z), acc[q][2]);
        acc[q][3] = fmaf(w, bf16_to_f32(u.w), acc[q][3]);
      }
    }
  }

  size_t ob = (size_t)node * DIM;
#pragma unroll
  for (int q = 0; q < 3; ++q) {
    int c = 4 * (lane + 64 * q);
    float4 bv = *(const float4*)(bias + c);
    float o0 = acc[q][0] + bv.x;
    float o1 = acc[q][1] + bv.y;
    float o2 = acc[q][2] + bv.z;
    float o3 = acc[q][3] + bv.w;
    if (relu_mode) {
      ushort4 st;
      st.x = f32_to_bf16(fmaxf(o0, 0.f));
      st.y = f32_to_bf16(fmaxf(o1, 0.f));
      st.z = f32_to_bf16(fmaxf(o2, 0.f));
      st.w = f32_to_bf16(fmaxf(o3, 0.f));
      *(ushort4*)(out_bf16 + ob + c) = st;
    } else {
      float4 st = make_float4(o0, o1, o2, o3);
      *(float4*)(out_f32 + ob + c) = st;
    }
  }
}

extern "C" void kernel_launch(void* const* d_in, const int* in_sizes, int n_in,
                              void* d_out, int out_size, void* d_ws, size_t ws_size,
                              hipStream_t stream) {
  const float* x   = (const float*)d_in[0];
  const int*   ei  = (const int*)d_in[1];
  const float* W1  = (const float*)d_in[2];
  const float* as1 = (const float*)d_in[3];
  const float* ad1 = (const float*)d_in[4];
  const float* b1  = (const float*)d_in[5];
  const float* W2  = (const float*)d_in[6];
  const float* as2 = (const float*)d_in[7];
  const float* ad2 = (const float*)d_in[8];
  const float* b2  = (const float*)d_in[9];

  const int N = in_sizes[0] / DIM;   // 10000
  const int E = in_sizes[1] / 2;     // 100000
  const int Etot = E + N;

  char* p = (char*)d_ws;
  auto alloc = [&](size_t bytes) {
    char* q = p;
    p += (bytes + 255) & ~(size_t)255;
    return q;
  };
  ushort_t* Hb     = (ushort_t*)alloc((size_t)N * DIM * 2);
  ushort_t* xb     = (ushort_t*)alloc((size_t)N * DIM * 2);
  ushort_t* wT1    = (ushort_t*)alloc((size_t)DIM * DIM * 2);
  ushort_t* wT2    = (ushort_t*)alloc((size_t)DIM * DIM * 2);
  // contiguous zeroed region: deg | a_s1 | a_d1 | a_s2 | a_d2  (one memset)
  int*      zbase  = (int*)alloc((size_t)5 * N * 4);
  int*      deg    = zbase;
  float*    a_s1   = (float*)(zbase + N);
  float*    a_d1   = (float*)(zbase + 2 * N);
  float*    a_s2   = (float*)(zbase + 3 * N);
  float*    a_d2   = (float*)(zbase + 4 * N);
  int*      rowst  = (int*)alloc((size_t)(N + 1) * 4);
  int*      cursor = (int*)alloc((size_t)N * 4);
  int*      col    = (int*)alloc((size_t)Etot * 4);

  hipMemsetAsync(zbase, 0, (size_t)5 * N * 4, stream);
  prep_kernel<<<(N * DIM / 4 + 255) / 256, 256, 0, stream>>>(x, xb, N * DIM / 4,
                                                             W1, wT1, W2, wT2);
  hist_kernel<<<(Etot + 255) / 256, 256, 0, stream>>>(ei, deg, E, Etot);
  scan_kernel<<<1, 256, 0, stream>>>(deg, rowst, cursor, N, Etot);
  fill_kernel<<<(Etot + 255) / 256, 256, 0, stream>>>(ei, cursor, col, E, Etot);

  dim3 ggrid((N + 127) / 128, DIM / 128);

  // Layer 1
  gemm_kernel<<<ggrid, 256, 0, stream>>>(xb, wT1, as1, ad1, a_s1, a_d1, Hb, N);
  aggregate_kernel<<<(N + 3) / 4, 256, 0, stream>>>(Hb, a_s1, a_d1, rowst, col, b1,
                                                    nullptr, xb, 1, N);
  // Layer 2
  gemm_kernel<<<ggrid, 256, 0, stream>>>(xb, wT2, as2, ad2, a_s2, a_d2, Hb, N);
  aggregate_kernel<<<(N + 3) / 4, 256, 0, stream>>>(Hb, a_s2, a_d2, rowst, col, b2,
                                                    (float*)d_out, nullptr, 0, N);
}

// Round 4
// 233.394 us; speedup vs baseline: 1.3739x; 1.0456x over previous
//
#include <hip/hip_runtime.h>

#define DIM 768
#define NEG_SLOPE 0.2f

typedef unsigned short ushort_t;
typedef short short8 __attribute__((ext_vector_type(8)));
typedef float floatx4 __attribute__((ext_vector_type(4)));

__device__ __forceinline__ ushort_t f32_to_bf16(float f) {
  unsigned int b = __float_as_uint(f);
  b += 0x7FFFu + ((b >> 16) & 1u);   // RNE
  return (ushort_t)(b >> 16);
}
__device__ __forceinline__ float bf16_to_f32(ushort_t u) {
  return __uint_as_float(((unsigned int)u) << 16);
}
__device__ __forceinline__ float bf16lo(unsigned int u) {
  return __uint_as_float(u << 16);
}
__device__ __forceinline__ float bf16hi(unsigned int u) {
  return __uint_as_float(u & 0xFFFF0000u);
}
__device__ __forceinline__ unsigned int pack_bf16x2(float lo, float hi) {
  return ((unsigned int)f32_to_bf16(lo)) | (((unsigned int)f32_to_bf16(hi)) << 16);
}

// async global->LDS, 16B per lane. LDS dest = wave-uniform base + lane*16.
__device__ __forceinline__ void gl2lds16(const ushort_t* g, ushort_t* l) {
  __builtin_amdgcn_global_load_lds(
      (const __attribute__((address_space(1))) void*)g,
      (__attribute__((address_space(3))) void*)l, 16, 0, 0);
}

// ---------------- fused prep: x->bf16 + both W transposes + zero scratch ----------
__global__ __launch_bounds__(256)
void prep_kernel(const float* __restrict__ x, ushort_t* __restrict__ xb, int n4,
                 const float* __restrict__ W1, ushort_t* __restrict__ wT1,
                 const float* __restrict__ W2, ushort_t* __restrict__ wT2,
                 int* __restrict__ zbase, int nz) {
  int i = blockIdx.x * 256 + threadIdx.x;
  if (i < n4) {
    float4 v = ((const float4*)x)[i];
    ushort4 o;
    o.x = f32_to_bf16(v.x); o.y = f32_to_bf16(v.y);
    o.z = f32_to_bf16(v.z); o.w = f32_to_bf16(v.w);
    ((ushort4*)xb)[i] = o;
  }
  if (i < DIM * DIM) {
    int nrow = i / DIM;
    int k = i - nrow * DIM;
    wT1[i] = f32_to_bf16(W1[k * DIM + nrow]);
    wT2[i] = f32_to_bf16(W2[k * DIM + nrow]);
  }
  if (i < nz) zbase[i] = 0;
}

// ---------------- CSR build (by destination, self-loops appended) ----------------
__global__ void hist_kernel(const int* __restrict__ ei, int* __restrict__ deg,
                            int E, int Etot) {
  int e = blockIdx.x * 256 + threadIdx.x;
  if (e >= Etot) return;
  int d = (e < E) ? ei[E + e] : (e - E);
  atomicAdd(&deg[d], 1);
}

__global__ __launch_bounds__(256)
void scan_kernel(const int* __restrict__ deg, int* __restrict__ rowstart,
                 int* __restrict__ cursor, int n, int etot) {
  __shared__ int sdeg[10240];
  __shared__ int part[256];
  int tid = threadIdx.x;
  for (int i = tid; i < n; i += 256) sdeg[i] = deg[i];
  __syncthreads();
  int chunk = ((n + 255) / 256) | 1;
  int lo = min(tid * chunk, n);
  int hi = min(lo + chunk, n);
  int s = 0;
  for (int i = lo; i < hi; ++i) s += sdeg[i];
  part[tid] = s;
  __syncthreads();
  for (int off = 1; off < 256; off <<= 1) {
    int v = part[tid];
    int add = (tid >= off) ? part[tid - off] : 0;
    __syncthreads();
    part[tid] = v + add;
    __syncthreads();
  }
  int run = (tid == 0) ? 0 : part[tid - 1];
  for (int i = lo; i < hi; ++i) {
    int d = sdeg[i];
    sdeg[i] = run;
    run += d;
  }
  __syncthreads();
  for (int i = tid; i < n; i += 256) {
    int v = sdeg[i];
    rowstart[i] = v;
    cursor[i] = v;
  }
  if (tid == 0) rowstart[n] = etot;
}

__global__ void fill_kernel(const int* __restrict__ ei, int* __restrict__ cursor,
                            int* __restrict__ col, int E, int Etot) {
  int e = blockIdx.x * 256 + threadIdx.x;
  if (e >= Etot) return;
  int s, d;
  if (e < E) { s = ei[e]; d = ei[E + e]; }
  else       { s = e - E; d = e - E; }
  int pos = atomicAdd(&cursor[d], 1);
  col[pos] = s;
}

// ---------------- bf16 MFMA GEMM, BK=64, global_load_lds staging ------------------
// C[M,768] = A[M,768] x (Bt)^T; writes Hb (bf16) + fused a_s/a_d (atomic, pre-zeroed).
// LDS rows are 64 elems (128 B); chunk-of-8 XOR swizzle (g ^ (row&7)) keeps the
// b128 fragment reads at 2-way bank alias (free). 12 K-iters (half the barriers
// of BK=32).
__global__ __launch_bounds__(256)
void gemm_kernel(const ushort_t* __restrict__ A, const ushort_t* __restrict__ Bt,
                 const float* __restrict__ att_s, const float* __restrict__ att_d,
                 float* __restrict__ a_s, float* __restrict__ a_d,
                 ushort_t* __restrict__ Hb, int M) {
  const int K = DIM;
  __shared__ __align__(16) ushort_t As[128 * 64];
  __shared__ __align__(16) ushort_t Bs[128 * 64];
  int tid = threadIdx.x;
  int m0 = blockIdx.x * 128, n0 = blockIdx.y * 128;
  int wave = tid >> 6, lane = tid & 63;
  int wm = (wave & 1) * 64, wn = (wave >> 1) * 64;
  int quad = lane >> 4, l16 = lane & 15;

  floatx4 acc[4][4];
  const floatx4 fzero = {0.f, 0.f, 0.f, 0.f};
#pragma unroll
  for (int i = 0; i < 4; ++i)
#pragma unroll
    for (int j = 0; j < 4; ++j) acc[i][j] = fzero;

  // staging geometry: call t covers rows [t*32 + wave*8, +8), lane = (lr<<3)|lc
  int lr = lane >> 3, lc = lane & 7;
  const ushort_t* gA[4];
  const ushort_t* gB[4];
  ushort_t* lA[4];
  ushort_t* lB[4];
#pragma unroll
  for (int t = 0; t < 4; ++t) {
    int r = t * 32 + wave * 8 + lr;
    int g = lc ^ (r & 7);
    gA[t] = A + (size_t)min(m0 + r, M - 1) * K + g * 8;
    gB[t] = Bt + (size_t)(n0 + r) * K + g * 8;
    lA[t] = As + (t * 32 + wave * 8) * 64;
    lB[t] = Bs + (t * 32 + wave * 8) * 64;
  }

  for (int k0 = 0; k0 < K; k0 += 64) {
#pragma unroll
    for (int t = 0; t < 4; ++t) {
      gl2lds16(gA[t] + k0, lA[t]);
      gl2lds16(gB[t] + k0, lB[t]);
    }
    __syncthreads();

#pragma unroll
    for (int h = 0; h < 2; ++h) {
      short8 af[4], bfr[4];
#pragma unroll
      for (int i = 0; i < 4; ++i) {
        int ra = wm + i * 16 + l16;
        af[i] = *(const short8*)(As + ra * 64 + ((((h << 2) | quad)) ^ (ra & 7)) * 8);
        int rb = wn + i * 16 + l16;
        bfr[i] = *(const short8*)(Bs + rb * 64 + ((((h << 2) | quad)) ^ (rb & 7)) * 8);
      }
#pragma unroll
      for (int i = 0; i < 4; ++i)
#pragma unroll
        for (int j = 0; j < 4; ++j)
          acc[i][j] = __builtin_amdgcn_mfma_f32_16x16x32_bf16(af[i], bfr[j], acc[i][j], 0, 0, 0);
    }
    __syncthreads();
  }

  float avs[4], avd[4];
#pragma unroll
  for (int j = 0; j < 4; ++j) {
    int c = n0 + wn + j * 16 + l16;
    avs[j] = att_s[c];
    avd[j] = att_d[c];
  }

#pragma unroll
  for (int i = 0; i < 4; ++i) {
#pragma unroll
    for (int r = 0; r < 4; ++r) {
      int row = m0 + wm + i * 16 + quad * 4 + r;
      bool valid = row < M;
      float pvs = 0.f, pvd = 0.f;
#pragma unroll
      for (int j = 0; j < 4; ++j) {
        float v = acc[i][j][r];
        if (valid) Hb[(size_t)row * DIM + n0 + wn + j * 16 + l16] = f32_to_bf16(v);
        pvs = fmaf(v, avs[j], pvs);
        pvd = fmaf(v, avd[j], pvd);
      }
#pragma unroll
      for (int off = 1; off < 16; off <<= 1) {
        pvs += __shfl_xor(pvs, off, 64);
        pvd += __shfl_xor(pvd, off, 64);
      }
      if (valid && l16 == 0) {
        atomicAdd(a_s + row, pvs);
        atomicAdd(a_d + row, pvd);
      }
    }
  }
}

// ---------------- wave-per-node segment softmax + gather-sum (bf16 h) ----------------
// Lane owns cols [lane*8, lane*8+8) + [512+lane*4, +4): one uint4 + one ushort4
// load per edge row.
__global__ __launch_bounds__(256)
void aggregate_kernel(const ushort_t* __restrict__ h, const float* __restrict__ a_s,
                      const float* __restrict__ a_d, const int* __restrict__ rowstart,
                      const int* __restrict__ col, const float* __restrict__ bias,
                      float* __restrict__ out_f32, ushort_t* __restrict__ out_bf16,
                      int relu_mode, int N) {
  int wave = threadIdx.x >> 6, lane = threadIdx.x & 63;
  int node = blockIdx.x * 4 + wave;
  if (node >= N) return;
  int start = rowstart[node], end = rowstart[node + 1];
  float ad = a_d[node];

  // pass 1: segment max of leaky_relu(a_s[src] + a_d[dst])
  float vmax = -3.4e38f;
  for (int e = start + lane; e < end; e += 64) {
    float v = a_s[col[e]] + ad;
    v = (v > 0.f) ? v : NEG_SLOPE * v;
    vmax = fmaxf(vmax, v);
  }
#pragma unroll
  for (int off = 32; off > 0; off >>= 1) vmax = fmaxf(vmax, __shfl_xor(vmax, off, 64));

  // pass 2: segment sum of exp
  float ssum = 0.f;
  for (int e = start + lane; e < end; e += 64) {
    float v = a_s[col[e]] + ad;
    v = (v > 0.f) ? v : NEG_SLOPE * v;
    ssum += __expf(v - vmax);
  }
#pragma unroll
  for (int off = 32; off > 0; off >>= 1) ssum += __shfl_xor(ssum, off, 64);
  float inv = 1.f / ssum;

  // pass 3: weighted gather
  float acc8[8];
  float acc4[4];
#pragma unroll
  for (int k = 0; k < 8; ++k) acc8[k] = 0.f;
#pragma unroll
  for (int k = 0; k < 4; ++k) acc4[k] = 0.f;

  for (int base = start; base < end; base += 64) {
    int e = base + lane;
    float al = 0.f;
    int sc = 0;
    if (e < end) {
      sc = col[e];
      float v = a_s[sc] + ad;
      v = (v > 0.f) ? v : NEG_SLOPE * v;
      al = __expf(v - vmax) * inv;
    }
    int cnt = min(64, end - base);
    for (int j = 0; j < cnt; ++j) {
      float w = __shfl(al, j, 64);
      int s = __shfl(sc, j, 64);
      const ushort_t* hr = h + (size_t)s * DIM;
      uint4 u = *(const uint4*)(hr + lane * 8);
      ushort4 t = *(const ushort4*)(hr + 512 + lane * 4);
      acc8[0] = fmaf(w, bf16lo(u.x), acc8[0]);
      acc8[1] = fmaf(w, bf16hi(u.x), acc8[1]);
      acc8[2] = fmaf(w, bf16lo(u.y), acc8[2]);
      acc8[3] = fmaf(w, bf16hi(u.y), acc8[3]);
      acc8[4] = fmaf(w, bf16lo(u.z), acc8[4]);
      acc8[5] = fmaf(w, bf16hi(u.z), acc8[5]);
      acc8[6] = fmaf(w, bf16lo(u.w), acc8[6]);
      acc8[7] = fmaf(w, bf16hi(u.w), acc8[7]);
      acc4[0] = fmaf(w, bf16_to_f32(t.x), acc4[0]);
      acc4[1] = fmaf(w, bf16_to_f32(t.y), acc4[1]);
      acc4[2] = fmaf(w, bf16_to_f32(t.z), acc4[2]);
      acc4[3] = fmaf(w, bf16_to_f32(t.w), acc4[3]);
    }
  }

  size_t ob = (size_t)node * DIM;
  int c8 = lane * 8, c4 = 512 + lane * 4;
  float4 b0 = *(const float4*)(bias + c8);
  float4 b1 = *(const float4*)(bias + c8 + 4);
  float4 b2 = *(const float4*)(bias + c4);
  float o[12];
  o[0] = acc8[0] + b0.x; o[1] = acc8[1] + b0.y;
  o[2] = acc8[2] + b0.z; o[3] = acc8[3] + b0.w;
  o[4] = acc8[4] + b1.x; o[5] = acc8[5] + b1.y;
  o[6] = acc8[6] + b1.z; o[7] = acc8[7] + b1.w;
  o[8] = acc4[0] + b2.x; o[9] = acc4[1] + b2.y;
  o[10] = acc4[2] + b2.z; o[11] = acc4[3] + b2.w;
  if (relu_mode) {
#pragma unroll
    for (int k = 0; k < 12; ++k) o[k] = fmaxf(o[k], 0.f);
    uint4 s0;
    s0.x = pack_bf16x2(o[0], o[1]);
    s0.y = pack_bf16x2(o[2], o[3]);
    s0.z = pack_bf16x2(o[4], o[5]);
    s0.w = pack_bf16x2(o[6], o[7]);
    *(uint4*)(out_bf16 + ob + c8) = s0;
    uint2 s1;
    s1.x = pack_bf16x2(o[8], o[9]);
    s1.y = pack_bf16x2(o[10], o[11]);
    *(uint2*)(out_bf16 + ob + c4) = s1;
  } else {
    *(float4*)(out_f32 + ob + c8) = make_float4(o[0], o[1], o[2], o[3]);
    *(float4*)(out_f32 + ob + c8 + 4) = make_float4(o[4], o[5], o[6], o[7]);
    *(float4*)(out_f32 + ob + c4) = make_float4(o[8], o[9], o[10], o[11]);
  }
}

extern "C" void kernel_launch(void* const* d_in, const int* in_sizes, int n_in,
                              void* d_out, int out_size, void* d_ws, size_t ws_size,
                              hipStream_t stream) {
  const float* x   = (const float*)d_in[0];
  const int*   ei  = (const int*)d_in[1];
  const float* W1  = (const float*)d_in[2];
  const float* as1 = (const float*)d_in[3];
  const float* ad1 = (const float*)d_in[4];
  const float* b1  = (const float*)d_in[5];
  const float* W2  = (const float*)d_in[6];
  const float* as2 = (const float*)d_in[7];
  const float* ad2 = (const float*)d_in[8];
  const float* b2  = (const float*)d_in[9];

  const int N = in_sizes[0] / DIM;   // 10000
  const int E = in_sizes[1] / 2;     // 100000
  const int Etot = E + N;

  char* p = (char*)d_ws;
  auto alloc = [&](size_t bytes) {
    char* q = p;
    p += (bytes + 255) & ~(size_t)255;
    return q;
  };
  ushort_t* Hb     = (ushort_t*)alloc((size_t)N * DIM * 2);
  ushort_t* xb     = (ushort_t*)alloc((size_t)N * DIM * 2);
  ushort_t* wT1    = (ushort_t*)alloc((size_t)DIM * DIM * 2);
  ushort_t* wT2    = (ushort_t*)alloc((size_t)DIM * DIM * 2);
  // contiguous zeroed region: deg | a_s1 | a_d1 | a_s2 | a_d2  (zeroed in prep)
  int*      zbase  = (int*)alloc((size_t)5 * N * 4);
  int*      deg    = zbase;
  float*    a_s1   = (float*)(zbase + N);
  float*    a_d1   = (float*)(zbase + 2 * N);
  float*    a_s2   = (float*)(zbase + 3 * N);
  float*    a_d2   = (float*)(zbase + 4 * N);
  int*      rowst  = (int*)alloc((size_t)(N + 1) * 4);
  int*      cursor = (int*)alloc((size_t)N * 4);
  int*      col    = (int*)alloc((size_t)Etot * 4);

  prep_kernel<<<(N * DIM / 4 + 255) / 256, 256, 0, stream>>>(
      x, xb, N * DIM / 4, W1, wT1, W2, wT2, zbase, 5 * N);
  hist_kernel<<<(Etot + 255) / 256, 256, 0, stream>>>(ei, deg, E, Etot);
  scan_kernel<<<1, 256, 0, stream>>>(deg, rowst, cursor, N, Etot);
  fill_kernel<<<(Etot + 255) / 256, 256, 0, stream>>>(ei, cursor, col, E, Etot);

  dim3 ggrid((N + 127) / 128, DIM / 128);

  // Layer 1
  gemm_kernel<<<ggrid, 256, 0, stream>>>(xb, wT1, as1, ad1, a_s1, a_d1, Hb, N);
  aggregate_kernel<<<(N + 3) / 4, 256, 0, stream>>>(Hb, a_s1, a_d1, rowst, col, b1,
                                                    nullptr, xb, 1, N);
  // Layer 2
  gemm_kernel<<<ggrid, 256, 0, stream>>>(xb, wT2, as2, ad2, a_s2, a_d2, Hb, N);
  aggregate_kernel<<<(N + 3) / 4, 256, 0, stream>>>(Hb, a_s2, a_d2, rowst, col, b2,
                                                    (float*)d_out, nullptr, 0, N);
}

// Round 5
// 232.909 us; speedup vs baseline: 1.3767x; 1.0021x over previous
//
#include <hip/hip_runtime.h>

#define DIM 768
#define NEG_SLOPE 0.2f

typedef unsigned short ushort_t;
typedef short short8 __attribute__((ext_vector_type(8)));
typedef float floatx4 __attribute__((ext_vector_type(4)));

__device__ __forceinline__ ushort_t f32_to_bf16(float f) {
  unsigned int b = __float_as_uint(f);
  b += 0x7FFFu + ((b >> 16) & 1u);   // RNE
  return (ushort_t)(b >> 16);
}
__device__ __forceinline__ float bf16_to_f32(ushort_t u) {
  return __uint_as_float(((unsigned int)u) << 16);
}
__device__ __forceinline__ float bf16lo(unsigned int u) {
  return __uint_as_float(u << 16);
}
__device__ __forceinline__ float bf16hi(unsigned int u) {
  return __uint_as_float(u & 0xFFFF0000u);
}
__device__ __forceinline__ unsigned int pack_bf16x2(float lo, float hi) {
  return ((unsigned int)f32_to_bf16(lo)) | (((unsigned int)f32_to_bf16(hi)) << 16);
}

// async global->LDS, 16B per lane. LDS dest = wave-uniform base + lane*16.
__device__ __forceinline__ void gl2lds16(const ushort_t* g, ushort_t* l) {
  __builtin_amdgcn_global_load_lds(
      (const __attribute__((address_space(1))) void*)g,
      (__attribute__((address_space(3))) void*)l, 16, 0, 0);
}

// ---------------- fused prep: x->bf16 + both W transposes + zero scratch ----------
__global__ __launch_bounds__(256)
void prep_kernel(const float* __restrict__ x, ushort_t* __restrict__ xb, int n4,
                 const float* __restrict__ W1, ushort_t* __restrict__ wT1,
                 const float* __restrict__ W2, ushort_t* __restrict__ wT2,
                 int* __restrict__ zbase, int nz) {
  int i = blockIdx.x * 256 + threadIdx.x;
  if (i < n4) {
    float4 v = ((const float4*)x)[i];
    ushort4 o;
    o.x = f32_to_bf16(v.x); o.y = f32_to_bf16(v.y);
    o.z = f32_to_bf16(v.z); o.w = f32_to_bf16(v.w);
    ((ushort4*)xb)[i] = o;
  }
  if (i < DIM * DIM) {
    int nrow = i / DIM;
    int k = i - nrow * DIM;
    wT1[i] = f32_to_bf16(W1[k * DIM + nrow]);
    wT2[i] = f32_to_bf16(W2[k * DIM + nrow]);
  }
  if (i < nz) zbase[i] = 0;
}

// ---------------- CSR build (by destination, self-loops appended) ----------------
__global__ void hist_kernel(const int* __restrict__ ei, int* __restrict__ deg,
                            int E, int Etot) {
  int e = blockIdx.x * 256 + threadIdx.x;
  if (e >= Etot) return;
  int d = (e < E) ? ei[E + e] : (e - E);
  atomicAdd(&deg[d], 1);
}

__global__ __launch_bounds__(256)
void scan_kernel(const int* __restrict__ deg, int* __restrict__ rowstart,
                 int* __restrict__ cursor, int n, int etot) {
  __shared__ int sdeg[10240];
  __shared__ int part[256];
  int tid = threadIdx.x;
  for (int i = tid; i < n; i += 256) sdeg[i] = deg[i];
  __syncthreads();
  int chunk = ((n + 255) / 256) | 1;
  int lo = min(tid * chunk, n);
  int hi = min(lo + chunk, n);
  int s = 0;
  for (int i = lo; i < hi; ++i) s += sdeg[i];
  part[tid] = s;
  __syncthreads();
  for (int off = 1; off < 256; off <<= 1) {
    int v = part[tid];
    int add = (tid >= off) ? part[tid - off] : 0;
    __syncthreads();
    part[tid] = v + add;
    __syncthreads();
  }
  int run = (tid == 0) ? 0 : part[tid - 1];
  for (int i = lo; i < hi; ++i) {
    int d = sdeg[i];
    sdeg[i] = run;
    run += d;
  }
  __syncthreads();
  for (int i = tid; i < n; i += 256) {
    int v = sdeg[i];
    rowstart[i] = v;
    cursor[i] = v;
  }
  if (tid == 0) rowstart[n] = etot;
}

__global__ void fill_kernel(const int* __restrict__ ei, int* __restrict__ cursor,
                            int* __restrict__ col, int E, int Etot) {
  int e = blockIdx.x * 256 + threadIdx.x;
  if (e >= Etot) return;
  int s, d;
  if (e < E) { s = ei[e]; d = ei[E + e]; }
  else       { s = e - E; d = e - E; }
  int pos = atomicAdd(&cursor[d], 1);
  col[pos] = s;
}

// ---------------- bf16 MFMA GEMM, 256x128 tile, 512 threads, BK=64 ----------------
// Grid = ceil(M/256) x 6 = 240 blocks <= 256 CUs: single occupancy pass, no tail.
// LDS rows 64 elems (128 B), chunk-of-8 XOR swizzle (g ^ (row&7)): fragment
// b128 reads stay 2-way bank-aliased (free). Writes Hb (bf16) + fused a_s/a_d.
__global__ __launch_bounds__(512)
void gemm_kernel(const ushort_t* __restrict__ A, const ushort_t* __restrict__ Bt,
                 const float* __restrict__ att_s, const float* __restrict__ att_d,
                 float* __restrict__ a_s, float* __restrict__ a_d,
                 ushort_t* __restrict__ Hb, int M) {
  const int K = DIM;
  __shared__ __align__(16) ushort_t As[256 * 64];   // 32 KB
  __shared__ __align__(16) ushort_t Bs[128 * 64];   // 16 KB
  int tid = threadIdx.x;
  int m0 = blockIdx.x * 256, n0 = blockIdx.y * 128;
  int wave = tid >> 6, lane = tid & 63;
  int wm = (wave >> 1) * 64, wn = (wave & 1) * 64;  // 4(M) x 2(N) waves
  int quad = lane >> 4, l16 = lane & 15;

  floatx4 acc[4][4];
  const floatx4 fzero = {0.f, 0.f, 0.f, 0.f};
#pragma unroll
  for (int i = 0; i < 4; ++i)
#pragma unroll
    for (int j = 0; j < 4; ++j) acc[i][j] = fzero;

  // staging: per wave-call 1 KB = 8 rows x 128 B; lane = (lr<<3)|lc
  int lr = lane >> 3, lc = lane & 7;
  const ushort_t* gA[4];
  const ushort_t* gB[2];
  ushort_t* lA[4];
  ushort_t* lB[2];
#pragma unroll
  for (int t = 0; t < 4; ++t) {
    int r = (wave * 4 + t) * 8 + lr;                 // 0..255
    int g = lc ^ (r & 7);
    gA[t] = A + (size_t)min(m0 + r, M - 1) * K + g * 8;
    lA[t] = As + (wave * 4 + t) * 8 * 64;
  }
#pragma unroll
  for (int t = 0; t < 2; ++t) {
    int r = (wave * 2 + t) * 8 + lr;                 // 0..127
    int g = lc ^ (r & 7);
    gB[t] = Bt + (size_t)(n0 + r) * K + g * 8;
    lB[t] = Bs + (wave * 2 + t) * 8 * 64;
  }

  for (int k0 = 0; k0 < K; k0 += 64) {
#pragma unroll
    for (int t = 0; t < 4; ++t) gl2lds16(gA[t] + k0, lA[t]);
#pragma unroll
    for (int t = 0; t < 2; ++t) gl2lds16(gB[t] + k0, lB[t]);
    __syncthreads();

#pragma unroll
    for (int h = 0; h < 2; ++h) {
      short8 af[4], bfr[4];
#pragma unroll
      for (int i = 0; i < 4; ++i) {
        int ra = wm + i * 16 + l16;
        af[i] = *(const short8*)(As + ra * 64 + ((((h << 2) | quad)) ^ (ra & 7)) * 8);
        int rb = wn + i * 16 + l16;
        bfr[i] = *(const short8*)(Bs + rb * 64 + ((((h << 2) | quad)) ^ (rb & 7)) * 8);
      }
#pragma unroll
      for (int i = 0; i < 4; ++i)
#pragma unroll
        for (int j = 0; j < 4; ++j)
          acc[i][j] = __builtin_amdgcn_mfma_f32_16x16x32_bf16(af[i], bfr[j], acc[i][j], 0, 0, 0);
    }
    __syncthreads();
  }

  float avs[4], avd[4];
#pragma unroll
  for (int j = 0; j < 4; ++j) {
    int c = n0 + wn + j * 16 + l16;
    avs[j] = att_s[c];
    avd[j] = att_d[c];
  }

#pragma unroll
  for (int i = 0; i < 4; ++i) {
#pragma unroll
    for (int r = 0; r < 4; ++r) {
      int row = m0 + wm + i * 16 + quad * 4 + r;
      bool valid = row < M;
      float pvs = 0.f, pvd = 0.f;
#pragma unroll
      for (int j = 0; j < 4; ++j) {
        float v = acc[i][j][r];
        if (valid) Hb[(size_t)row * DIM + n0 + wn + j * 16 + l16] = f32_to_bf16(v);
        pvs = fmaf(v, avs[j], pvs);
        pvd = fmaf(v, avd[j], pvd);
      }
#pragma unroll
      for (int off = 1; off < 16; off <<= 1) {
        pvs += __shfl_xor(pvs, off, 64);
        pvd += __shfl_xor(pvd, off, 64);
      }
      if (valid && l16 == 0) {
        atomicAdd(a_s + row, pvs);
        atomicAdd(a_d + row, pvd);
      }
    }
  }
}

// ---------------- wave-per-node segment softmax + gather-sum (bf16 h) ----------------
__global__ __launch_bounds__(256)
void aggregate_kernel(const ushort_t* __restrict__ h, const float* __restrict__ a_s,
                      const float* __restrict__ a_d, const int* __restrict__ rowstart,
                      const int* __restrict__ col, const float* __restrict__ bias,
                      float* __restrict__ out_f32, ushort_t* __restrict__ out_bf16,
                      int relu_mode, int N) {
  int wave = threadIdx.x >> 6, lane = threadIdx.x & 63;
  int node = blockIdx.x * 4 + wave;
  if (node >= N) return;
  int start = rowstart[node], end = rowstart[node + 1];
  float ad = a_d[node];

  float vmax = -3.4e38f;
  for (int e = start + lane; e < end; e += 64) {
    float v = a_s[col[e]] + ad;
    v = (v > 0.f) ? v : NEG_SLOPE * v;
    vmax = fmaxf(vmax, v);
  }
#pragma unroll
  for (int off = 32; off > 0; off >>= 1) vmax = fmaxf(vmax, __shfl_xor(vmax, off, 64));

  float ssum = 0.f;
  for (int e = start + lane; e < end; e += 64) {
    float v = a_s[col[e]] + ad;
    v = (v > 0.f) ? v : NEG_SLOPE * v;
    ssum += __expf(v - vmax);
  }
#pragma unroll
  for (int off = 32; off > 0; off >>= 1) ssum += __shfl_xor(ssum, off, 64);
  float inv = 1.f / ssum;

  float acc8[8];
  float acc4[4];
#pragma unroll
  for (int k = 0; k < 8; ++k) acc8[k] = 0.f;
#pragma unroll
  for (int k = 0; k < 4; ++k) acc4[k] = 0.f;

  for (int base = start; base < end; base += 64) {
    int e = base + lane;
    float al = 0.f;
    int sc = 0;
    if (e < end) {
      sc = col[e];
      float v = a_s[sc] + ad;
      v = (v > 0.f) ? v : NEG_SLOPE * v;
      al = __expf(v - vmax) * inv;
    }
    int cnt = min(64, end - base);
    for (int j = 0; j < cnt; ++j) {
      float w = __shfl(al, j, 64);
      int s = __shfl(sc, j, 64);
      const ushort_t* hr = h + (size_t)s * DIM;
      uint4 u = *(const uint4*)(hr + lane * 8);
      ushort4 t = *(const ushort4*)(hr + 512 + lane * 4);
      acc8[0] = fmaf(w, bf16lo(u.x), acc8[0]);
      acc8[1] = fmaf(w, bf16hi(u.x), acc8[1]);
      acc8[2] = fmaf(w, bf16lo(u.y), acc8[2]);
      acc8[3] = fmaf(w, bf16hi(u.y), acc8[3]);
      acc8[4] = fmaf(w, bf16lo(u.z), acc8[4]);
      acc8[5] = fmaf(w, bf16hi(u.z), acc8[5]);
      acc8[6] = fmaf(w, bf16lo(u.w), acc8[6]);
      acc8[7] = fmaf(w, bf16hi(u.w), acc8[7]);
      acc4[0] = fmaf(w, bf16_to_f32(t.x), acc4[0]);
      acc4[1] = fmaf(w, bf16_to_f32(t.y), acc4[1]);
      acc4[2] = fmaf(w, bf16_to_f32(t.z), acc4[2]);
      acc4[3] = fmaf(w, bf16_to_f32(t.w), acc4[3]);
    }
  }

  size_t ob = (size_t)node * DIM;
  int c8 = lane * 8, c4 = 512 + lane * 4;
  float4 b0 = *(const float4*)(bias + c8);
  float4 b1 = *(const float4*)(bias + c8 + 4);
  float4 b2 = *(const float4*)(bias + c4);
  float o[12];
  o[0] = acc8[0] + b0.x; o[1] = acc8[1] + b0.y;
  o[2] = acc8[2] + b0.z; o[3] = acc8[3] + b0.w;
  o[4] = acc8[4] + b1.x; o[5] = acc8[5] + b1.y;
  o[6] = acc8[6] + b1.z; o[7] = acc8[7] + b1.w;
  o[8] = acc4[0] + b2.x; o[9] = acc4[1] + b2.y;
  o[10] = acc4[2] + b2.z; o[11] = acc4[3] + b2.w;
  if (relu_mode) {
#pragma unroll
    for (int k = 0; k < 12; ++k) o[k] = fmaxf(o[k], 0.f);
    uint4 s0;
    s0.x = pack_bf16x2(o[0], o[1]);
    s0.y = pack_bf16x2(o[2], o[3]);
    s0.z = pack_bf16x2(o[4], o[5]);
    s0.w = pack_bf16x2(o[6], o[7]);
    *(uint4*)(out_bf16 + ob + c8) = s0;
    uint2 s1;
    s1.x = pack_bf16x2(o[8], o[9]);
    s1.y = pack_bf16x2(o[10], o[11]);
    *(uint2*)(out_bf16 + ob + c4) = s1;
  } else {
    *(float4*)(out_f32 + ob + c8) = make_float4(o[0], o[1], o[2], o[3]);
    *(float4*)(out_f32 + ob + c8 + 4) = make_float4(o[4], o[5], o[6], o[7]);
    *(float4*)(out_f32 + ob + c4) = make_float4(o[8], o[9], o[10], o[11]);
  }
}

extern "C" void kernel_launch(void* const* d_in, const int* in_sizes, int n_in,
                              void* d_out, int out_size, void* d_ws, size_t ws_size,
                              hipStream_t stream) {
  const float* x   = (const float*)d_in[0];
  const int*   ei  = (const int*)d_in[1];
  const float* W1  = (const float*)d_in[2];
  const float* as1 = (const float*)d_in[3];
  const float* ad1 = (const float*)d_in[4];
  const float* b1  = (const float*)d_in[5];
  const float* W2  = (const float*)d_in[6];
  const float* as2 = (const float*)d_in[7];
  const float* ad2 = (const float*)d_in[8];
  const float* b2  = (const float*)d_in[9];

  const int N = in_sizes[0] / DIM;   // 10000
  const int E = in_sizes[1] / 2;     // 100000
  const int Etot = E + N;

  char* p = (char*)d_ws;
  auto alloc = [&](size_t bytes) {
    char* q = p;
    p += (bytes + 255) & ~(size_t)255;
    return q;
  };
  ushort_t* Hb     = (ushort_t*)alloc((size_t)N * DIM * 2);
  ushort_t* xb     = (ushort_t*)alloc((size_t)N * DIM * 2);
  ushort_t* wT1    = (ushort_t*)alloc((size_t)DIM * DIM * 2);
  ushort_t* wT2    = (ushort_t*)alloc((size_t)DIM * DIM * 2);
  // contiguous zeroed region: deg | a_s1 | a_d1 | a_s2 | a_d2  (zeroed in prep)
  int*      zbase  = (int*)alloc((size_t)5 * N * 4);
  int*      deg    = zbase;
  float*    a_s1   = (float*)(zbase + N);
  float*    a_d1   = (float*)(zbase + 2 * N);
  float*    a_s2   = (float*)(zbase + 3 * N);
  float*    a_d2   = (float*)(zbase + 4 * N);
  int*      rowst  = (int*)alloc((size_t)(N + 1) * 4);
  int*      cursor = (int*)alloc((size_t)N * 4);
  int*      col    = (int*)alloc((size_t)Etot * 4);

  prep_kernel<<<(N * DIM / 4 + 255) / 256, 256, 0, stream>>>(
      x, xb, N * DIM / 4, W1, wT1, W2, wT2, zbase, 5 * N);
  hist_kernel<<<(Etot + 255) / 256, 256, 0, stream>>>(ei, deg, E, Etot);
  scan_kernel<<<1, 256, 0, stream>>>(deg, rowst, cursor, N, Etot);
  fill_kernel<<<(Etot + 255) / 256, 256, 0, stream>>>(ei, cursor, col, E, Etot);

  dim3 ggrid((N + 255) / 256, DIM / 128);   // 40 x 6 = 240 blocks: single pass

  // Layer 1
  gemm_kernel<<<ggrid, 512, 0, stream>>>(xb, wT1, as1, ad1, a_s1, a_d1, Hb, N);
  aggregate_kernel<<<(N + 3) / 4, 256, 0, stream>>>(Hb, a_s1, a_d1, rowst, col, b1,
                                                    nullptr, xb, 1, N);
  // Layer 2
  gemm_kernel<<<ggrid, 512, 0, stream>>>(xb, wT2, as2, ad2, a_s2, a_d2, Hb, N);
  aggregate_kernel<<<(N + 3) / 4, 256, 0, stream>>>(Hb, a_s2, a_d2, rowst, col, b2,
                                                    (float*)d_out, nullptr, 0, N);
}